// Round 2
// baseline (328.664 us; speedup 1.0000x reference)
//
#include <hip/hip_runtime.h>

// MHA: B=2, S=2048, D=1024, H=16, HD=64, causal, scale=1/8.
// Round 2: fix QKV output offset bug (z-slice was unapplied -> K/Vt never
// written, attn read poison). Otherwise identical to round 1.
//   ws layout (bytes):
//     [0,8M)    Xbf  : x as bf16 [4096,1024]
//     [8M,16M)  WT   : WqT,WkT,WvT,WoT bf16 [1024,1024] each (B^T layout [N][K])
//     [16M,40M) QKV  : Q [B,H,S,HD], K [B,H,S,HD], Vt [B,H,HD,S] bf16
//     [40M,48M) ctx  : attention output bf16 [B,S,D]

#define S_LEN 2048
#define DMODEL 1024
#define NHEAD 16
#define HDIM 64
#define MROWS 4096  // B*S

typedef __bf16 bf16x8 __attribute__((ext_vector_type(8)));
typedef float f32x4 __attribute__((ext_vector_type(4)));

__device__ __forceinline__ ushort f2bf(float f) {
  union { float f; unsigned u; } v; v.f = f;
  unsigned r = v.u + 0x7fffu + ((v.u >> 16) & 1u);  // RNE
  return (ushort)(r >> 16);
}

__device__ __forceinline__ void gload_lds16(const ushort* g, ushort* l) {
  __builtin_amdgcn_global_load_lds(
      (const __attribute__((address_space(1))) void*)g,
      (__attribute__((address_space(3))) void*)l, 16, 0, 0);
}

// ---------------- conversion kernels ----------------

__global__ __launch_bounds__(256) void cvt_x(const float* __restrict__ x,
                                             ushort* __restrict__ xb) {
  int i = (blockIdx.x * 256 + threadIdx.x) * 4;
  float4 v = *(const float4*)&x[i];
  ushort4 o;
  o.x = f2bf(v.x); o.y = f2bf(v.y); o.z = f2bf(v.z); o.w = f2bf(v.w);
  *(ushort4*)&xb[i] = o;
}

// W [K][N] fp32 -> WT [N][K] bf16 (so GEMM B-fragments are contiguous)
__global__ __launch_bounds__(256) void cvt_wt(const float* __restrict__ W0,
                                              const float* __restrict__ W1,
                                              const float* __restrict__ W2,
                                              const float* __restrict__ W3,
                                              ushort* __restrict__ out) {
  const float* W = blockIdx.z == 0 ? W0 : blockIdx.z == 1 ? W1
                   : blockIdx.z == 2 ? W2 : W3;
  ushort* WT = out + (size_t)blockIdx.z * DMODEL * DMODEL;
  __shared__ float tile[32][33];
  int n0 = blockIdx.x * 32, k0 = blockIdx.y * 32;
  int tx = threadIdx.x & 31, ty = threadIdx.x >> 5;  // 32 x 8
#pragma unroll
  for (int i = 0; i < 32; i += 8)
    tile[ty + i][tx] = W[(size_t)(k0 + ty + i) * DMODEL + n0 + tx];
  __syncthreads();
#pragma unroll
  for (int i = 0; i < 32; i += 8)
    WT[(size_t)(n0 + ty + i) * DMODEL + k0 + tx] = f2bf(tile[tx][ty + i]);
}

// ---------------- GEMM (128x128 tile, BK=64, 4 waves, m97 structure) -------
// A [M,K] bf16 row-major; Bt [N,K] bf16 row-major; C = A*B^T(Bt) + bias.
// MODE 0: QKV (grid.z selects W/bias; writes bf16 at z-offset, z<2 ->
//         [B,H,S,HD], z==2 -> [B,H,HD,S]).  MODE 1: fp32 plain [M,N] out.

template <int MODE>
__global__ __launch_bounds__(256) void gemm128(
    const ushort* __restrict__ A, const ushort* __restrict__ BtB,
    const float* __restrict__ b0, const float* __restrict__ b1,
    const float* __restrict__ b2, void* __restrict__ outB) {
  const int z = (MODE == 0) ? blockIdx.z : 0;
  const ushort* Bt = BtB + (size_t)z * DMODEL * DMODEL;
  const float* bias = (MODE == 0) ? (z == 0 ? b0 : z == 1 ? b1 : b2) : b0;

  __shared__ __align__(16) ushort Alds[128 * 64];
  __shared__ __align__(16) ushort Blds[128 * 64];

  const int tid = threadIdx.x;
  const int lane = tid & 63, w = tid >> 6;
  const int wr = w >> 1, wc = w & 1;            // 2x2 waves of 64x64
  const int m0 = blockIdx.x * 128, n0 = blockIdx.y * 128;
  const int fr = lane & 15, fk = (lane >> 4) * 8;

  f32x4 acc[4][4] = {};

  for (int kt = 0; kt < DMODEL; kt += 64) {
    __syncthreads();  // prev iter's LDS reads done before overwrite
#pragma unroll
    for (int it = 0; it < 4; ++it) {
      int c = it * 256 + tid;              // 16B chunk index
      int row = c >> 3, col = (c & 7) * 8;
      int ldsbase = (it * 256 + w * 64) * 8;  // wave-uniform dest
      gload_lds16(&A[(size_t)(m0 + row) * DMODEL + kt + col], &Alds[ldsbase]);
      gload_lds16(&Bt[(size_t)(n0 + row) * DMODEL + kt + col], &Blds[ldsbase]);
    }
    __syncthreads();  // implies vmcnt(0): staging complete
#pragma unroll
    for (int kk = 0; kk < 2; ++kk) {
      bf16x8 af[4], bf[4];
#pragma unroll
      for (int i = 0; i < 4; ++i)
        af[i] = *(const bf16x8*)&Alds[(wr * 64 + i * 16 + fr) * 64 + kk * 32 + fk];
#pragma unroll
      for (int j = 0; j < 4; ++j)
        bf[j] = *(const bf16x8*)&Blds[(wc * 64 + j * 16 + fr) * 64 + kk * 32 + fk];
#pragma unroll
      for (int i = 0; i < 4; ++i)
#pragma unroll
        for (int j = 0; j < 4; ++j)
          acc[i][j] = __builtin_amdgcn_mfma_f32_16x16x32_bf16(af[i], bf[j],
                                                              acc[i][j], 0, 0, 0);
    }
  }

#pragma unroll
  for (int i = 0; i < 4; ++i) {
#pragma unroll
    for (int j = 0; j < 4; ++j) {
      int col = n0 + wc * 64 + j * 16 + fr;
      float bval = bias[col];
#pragma unroll
      for (int r = 0; r < 4; ++r) {
        int row = m0 + wr * 64 + i * 16 + (lane >> 4) * 4 + r;
        float val = acc[i][j][r] + bval;
        if (MODE == 0) {
          int b = row >> 11, s = row & (S_LEN - 1);
          int h = col >> 6, hd = col & (HDIM - 1);
          size_t idx;
          if (z < 2) idx = (((size_t)(b * NHEAD + h)) * S_LEN + s) * HDIM + hd;
          else       idx = (((size_t)(b * NHEAD + h)) * HDIM + hd) * S_LEN + s;
          // z-slice offset: Q at 0, K at +4M, Vt at +8M elements
          ((ushort*)outB)[(size_t)z * MROWS * DMODEL + idx] = f2bf(val);
        } else {
          ((float*)outB)[(size_t)row * DMODEL + col] = val;
        }
      }
    }
  }
}

// ---------------- flash attention (causal) ----------------
// 1 wave per (b,h, 16-row q block); KV blocks of 32.
__global__ __launch_bounds__(64) void attn(const ushort* __restrict__ Q,
                                           const ushort* __restrict__ K,
                                           const ushort* __restrict__ Vt,
                                           ushort* __restrict__ ctx) {
  const int qb = blockIdx.x;   // 0..127
  const int bh = blockIdx.y;   // 0..31
  const int b = bh >> 4, h = bh & 15;
  const int lane = threadIdx.x;
  const int fr = lane & 15, g = lane >> 4, fk = g * 8;
  const int qbase = qb * 16;

  const ushort* Qb = Q + ((size_t)bh * S_LEN + qbase) * HDIM;
  const ushort* Kb = K + (size_t)bh * S_LEN * HDIM;
  const ushort* Vb = Vt + (size_t)bh * HDIM * S_LEN;

  bf16x8 qf[2];
  qf[0] = *(const bf16x8*)&Qb[fr * HDIM + fk];
  qf[1] = *(const bf16x8*)&Qb[fr * HDIM + 32 + fk];

  float m[4], lsum[4];
  f32x4 oacc[4] = {};  // [hd-tile][r] ; row=g*4+r, col=nh*16+fr
#pragma unroll
  for (int r = 0; r < 4; ++r) { m[r] = -1e30f; lsum[r] = 0.f; }

  __shared__ __align__(16) ushort Plds[16 * 32];

  const int nblk = (qbase + 16 + 31) >> 5;
  for (int kb = 0; kb < nblk; ++kb) {
    const int kv0 = kb * 32;
    f32x4 sa[2] = {};
#pragma unroll
    for (int n = 0; n < 2; ++n)
#pragma unroll
      for (int c = 0; c < 2; ++c) {
        bf16x8 kf = *(const bf16x8*)&Kb[(size_t)(kv0 + n * 16 + fr) * HDIM + c * 32 + fk];
        sa[n] = __builtin_amdgcn_mfma_f32_16x16x32_bf16(qf[c], kf, sa[n], 0, 0, 0);
      }
    const bool need_mask = (kv0 + 31) > qbase;
    float s[2][4];
#pragma unroll
    for (int n = 0; n < 2; ++n)
#pragma unroll
      for (int r = 0; r < 4; ++r) {
        float v = sa[n][r] * 0.125f;
        if (need_mask) {
          int colg = kv0 + n * 16 + fr;
          int rowg = qbase + g * 4 + r;
          if (colg > rowg) v = -1e30f;
        }
        s[n][r] = v;
      }
    float tm[4];
#pragma unroll
    for (int r = 0; r < 4; ++r) tm[r] = fmaxf(s[0][r], s[1][r]);
#pragma unroll
    for (int d = 1; d < 16; d <<= 1)
#pragma unroll
      for (int r = 0; r < 4; ++r) tm[r] = fmaxf(tm[r], __shfl_xor(tm[r], d, 64));
    float alpha[4], ps[4], p[2][4];
#pragma unroll
    for (int r = 0; r < 4; ++r) {
      float mn = fmaxf(m[r], tm[r]);
      alpha[r] = __expf(m[r] - mn);
      m[r] = mn;
      p[0][r] = __expf(s[0][r] - mn);
      p[1][r] = __expf(s[1][r] - mn);
      ps[r] = p[0][r] + p[1][r];
    }
#pragma unroll
    for (int d = 1; d < 16; d <<= 1)
#pragma unroll
      for (int r = 0; r < 4; ++r) ps[r] += __shfl_xor(ps[r], d, 64);
#pragma unroll
    for (int r = 0; r < 4; ++r) lsum[r] = lsum[r] * alpha[r] + ps[r];
#pragma unroll
    for (int nh = 0; nh < 4; ++nh)
#pragma unroll
      for (int r = 0; r < 4; ++r) oacc[nh][r] *= alpha[r];

    __syncthreads();  // prev P reads done (single wave: cheap)
#pragma unroll
    for (int n = 0; n < 2; ++n)
#pragma unroll
      for (int r = 0; r < 4; ++r)
        Plds[(g * 4 + r) * 32 + n * 16 + fr] = f2bf(p[n][r]);
    __syncthreads();  // P writes visible (lgkmcnt drained)

    bf16x8 pf = *(const bf16x8*)&Plds[fr * 32 + fk];
#pragma unroll
    for (int nh = 0; nh < 4; ++nh) {
      bf16x8 vf = *(const bf16x8*)&Vb[(size_t)(nh * 16 + fr) * S_LEN + kv0 + fk];
      oacc[nh] = __builtin_amdgcn_mfma_f32_16x16x32_bf16(pf, vf, oacc[nh], 0, 0, 0);
    }
  }

  float linv[4];
#pragma unroll
  for (int r = 0; r < 4; ++r) linv[r] = 1.0f / lsum[r];
#pragma unroll
  for (int nh = 0; nh < 4; ++nh)
#pragma unroll
    for (int r = 0; r < 4; ++r) {
      int row = qbase + g * 4 + r;
      int col = h * HDIM + nh * 16 + fr;
      ctx[((size_t)(b * S_LEN) + row) * DMODEL + col] = f2bf(oacc[nh][r] * linv[r]);
    }
}

// ---------------- launch ----------------

extern "C" void kernel_launch(void* const* d_in, const int* in_sizes, int n_in,
                              void* d_out, int out_size, void* d_ws,
                              size_t ws_size, hipStream_t stream) {
  const float* x  = (const float*)d_in[0];
  const float* Wq = (const float*)d_in[1];
  const float* bq = (const float*)d_in[2];
  const float* Wk = (const float*)d_in[3];
  const float* bk = (const float*)d_in[4];
  const float* Wv = (const float*)d_in[5];
  const float* bv = (const float*)d_in[6];
  const float* Wo = (const float*)d_in[7];
  const float* bo = (const float*)d_in[8];

  char* ws = (char*)d_ws;
  ushort* Xbf = (ushort*)ws;                               // 8 MB
  ushort* WT  = (ushort*)(ws + (size_t)8 * 1024 * 1024);   // 8 MB
  ushort* QKV = (ushort*)(ws + (size_t)16 * 1024 * 1024);  // 24 MB
  ushort* CTX = (ushort*)(ws + (size_t)40 * 1024 * 1024);  // 8 MB

  const size_t QKV_ELEMS = (size_t)MROWS * DMODEL;  // 4194304 per tensor
  const size_t W_ELEMS = (size_t)DMODEL * DMODEL;

  cvt_x<<<4096, 256, 0, stream>>>(x, Xbf);
  cvt_wt<<<dim3(32, 32, 4), 256, 0, stream>>>(Wq, Wk, Wv, Wo, WT);
  gemm128<0><<<dim3(32, 8, 3), 256, 0, stream>>>(Xbf, WT, bq, bk, bv, QKV);
  attn<<<dim3(128, 32), 64, 0, stream>>>(QKV, QKV + QKV_ELEMS,
                                         QKV + 2 * QKV_ELEMS, CTX);
  gemm128<1><<<dim3(32, 8), 256, 0, stream>>>(CTX, WT + 3 * W_ELEMS, bo,
                                              nullptr, nullptr, d_out);
}

// Round 5
// 216.404 us; speedup vs baseline: 1.5188x; 1.5188x over previous
//
#include <hip/hip_runtime.h>

// MHA: B=2, S=2048, D=1024, H=16, HD=64, causal, scale=1/8.
// Round 5: fix divergent-shfl hazard — all __shfl_xor hoisted to unconditional
// full-wave execution (convergent), selects via register cndmask. Structure
// unchanged: 4-wave blocks, QBLK=32/wave, KVBLK=64, swapped QK^T, in-register
// softmax, defer-max, setprio.
//   ws layout (bytes):
//     [0,8M)    Xbf  : x as bf16 [4096,1024]
//     [8M,16M)  WT   : WqT,WkT,WvT,WoT bf16 [1024,1024] each ([N][K])
//     [16M,40M) QKV  : Q [B,H,S,HD], K [B,H,S,HD], Vt [B,H,HD,S] bf16
//     [40M,48M) ctx  : attention output bf16 [B,S,D]

#define S_LEN 2048
#define DMODEL 1024
#define NHEAD 16
#define HDIM 64
#define MROWS 4096  // B*S

typedef __bf16 bf16x8 __attribute__((ext_vector_type(8)));
typedef float f32x4 __attribute__((ext_vector_type(4)));
typedef float f32x16 __attribute__((ext_vector_type(16)));

__device__ __forceinline__ ushort f2bf(float f) {
  union { float f; unsigned u; } v; v.f = f;
  unsigned r = v.u + 0x7fffu + ((v.u >> 16) & 1u);  // RNE
  return (ushort)(r >> 16);
}

__device__ __forceinline__ void gload_lds16(const ushort* g, ushort* l) {
  __builtin_amdgcn_global_load_lds(
      (const __attribute__((address_space(1))) void*)g,
      (__attribute__((address_space(3))) void*)l, 16, 0, 0);
}

// pack two f32 -> one dword of 2 bf16 (compiler emits v_cvt_pk_bf16_f32)
__device__ __forceinline__ unsigned pack2bf(float lo, float hi) {
  union { __bf16 h[2]; unsigned u; } t;
  t.h[0] = (__bf16)lo; t.h[1] = (__bf16)hi;
  return t.u;
}

// ---------------- conversion kernels ----------------

__global__ __launch_bounds__(256) void cvt_x(const float* __restrict__ x,
                                             ushort* __restrict__ xb) {
  int i = (blockIdx.x * 256 + threadIdx.x) * 4;
  float4 v = *(const float4*)&x[i];
  ushort4 o;
  o.x = f2bf(v.x); o.y = f2bf(v.y); o.z = f2bf(v.z); o.w = f2bf(v.w);
  *(ushort4*)&xb[i] = o;
}

// W [K][N] fp32 -> WT [N][K] bf16
__global__ __launch_bounds__(256) void cvt_wt(const float* __restrict__ W0,
                                              const float* __restrict__ W1,
                                              const float* __restrict__ W2,
                                              const float* __restrict__ W3,
                                              ushort* __restrict__ out) {
  const float* W = blockIdx.z == 0 ? W0 : blockIdx.z == 1 ? W1
                   : blockIdx.z == 2 ? W2 : W3;
  ushort* WT = out + (size_t)blockIdx.z * DMODEL * DMODEL;
  __shared__ float tile[32][33];
  int n0 = blockIdx.x * 32, k0 = blockIdx.y * 32;
  int tx = threadIdx.x & 31, ty = threadIdx.x >> 5;  // 32 x 8
#pragma unroll
  for (int i = 0; i < 32; i += 8)
    tile[ty + i][tx] = W[(size_t)(k0 + ty + i) * DMODEL + n0 + tx];
  __syncthreads();
#pragma unroll
  for (int i = 0; i < 32; i += 8)
    WT[(size_t)(n0 + ty + i) * DMODEL + k0 + tx] = f2bf(tile[tx][ty + i]);
}

// ---------------- GEMM (128x128 tile, BK=64, 4 waves) ----------------

template <int MODE>
__global__ __launch_bounds__(256) void gemm128(
    const ushort* __restrict__ A, const ushort* __restrict__ BtB,
    const float* __restrict__ b0, const float* __restrict__ b1,
    const float* __restrict__ b2, void* __restrict__ outB) {
  const int z = (MODE == 0) ? blockIdx.z : 0;
  const ushort* Bt = BtB + (size_t)z * DMODEL * DMODEL;
  const float* bias = (MODE == 0) ? (z == 0 ? b0 : z == 1 ? b1 : b2) : b0;

  __shared__ __align__(16) ushort Alds[128 * 64];
  __shared__ __align__(16) ushort Blds[128 * 64];

  const int tid = threadIdx.x;
  const int lane = tid & 63, w = tid >> 6;
  const int wr = w >> 1, wc = w & 1;
  const int m0 = blockIdx.x * 128, n0 = blockIdx.y * 128;
  const int fr = lane & 15, fk = (lane >> 4) * 8;

  f32x4 acc[4][4] = {};

  for (int kt = 0; kt < DMODEL; kt += 64) {
    __syncthreads();
#pragma unroll
    for (int it = 0; it < 4; ++it) {
      int c = it * 256 + tid;
      int row = c >> 3, col = (c & 7) * 8;
      int ldsbase = (it * 256 + w * 64) * 8;
      gload_lds16(&A[(size_t)(m0 + row) * DMODEL + kt + col], &Alds[ldsbase]);
      gload_lds16(&Bt[(size_t)(n0 + row) * DMODEL + kt + col], &Blds[ldsbase]);
    }
    __syncthreads();
#pragma unroll
    for (int kk = 0; kk < 2; ++kk) {
      bf16x8 af[4], bfr[4];
#pragma unroll
      for (int i = 0; i < 4; ++i)
        af[i] = *(const bf16x8*)&Alds[(wr * 64 + i * 16 + fr) * 64 + kk * 32 + fk];
#pragma unroll
      for (int j = 0; j < 4; ++j)
        bfr[j] = *(const bf16x8*)&Blds[(wc * 64 + j * 16 + fr) * 64 + kk * 32 + fk];
#pragma unroll
      for (int i = 0; i < 4; ++i)
#pragma unroll
        for (int j = 0; j < 4; ++j)
          acc[i][j] = __builtin_amdgcn_mfma_f32_16x16x32_bf16(af[i], bfr[j],
                                                              acc[i][j], 0, 0, 0);
    }
  }

#pragma unroll
  for (int i = 0; i < 4; ++i) {
#pragma unroll
    for (int j = 0; j < 4; ++j) {
      int col = n0 + wc * 64 + j * 16 + fr;
      float bval = bias[col];
#pragma unroll
      for (int r = 0; r < 4; ++r) {
        int row = m0 + wr * 64 + i * 16 + (lane >> 4) * 4 + r;
        float val = acc[i][j][r] + bval;
        if (MODE == 0) {
          int b = row >> 11, s = row & (S_LEN - 1);
          int h = col >> 6, hd = col & (HDIM - 1);
          size_t idx;
          if (z < 2) idx = (((size_t)(b * NHEAD + h)) * S_LEN + s) * HDIM + hd;
          else       idx = (((size_t)(b * NHEAD + h)) * HDIM + hd) * S_LEN + s;
          ((ushort*)outB)[(size_t)z * MROWS * DMODEL + idx] = f2bf(val);
        } else {
          ((float*)outB)[(size_t)row * DMODEL + col] = val;
        }
      }
    }
  }
}

// ---------------- flash attention (causal), swapped-QK^T ----------------
// Grid: 512 blocks x 256 thr. Each wave owns 32 q-rows; KVBLK=64.
// S^T = K.Q^T via mfma_32x32x16: lane owns q=lane&31 column; k rows split
// lane/lane^32 per C-layout row=(r&3)+8*(r>>2)+4*(lane>>5).
__global__ __launch_bounds__(256) void attn2(const ushort* __restrict__ Q,
                                             const ushort* __restrict__ K,
                                             const ushort* __restrict__ Vt,
                                             ushort* __restrict__ ctx) {
  const int n = blockIdx.x;
  const int v = (n & 7) * 64 + (n >> 3);  // bijective XCD-contiguous (512=8*64)
  const int qb = v & 15, bh = v >> 4;
  const int b = bh >> 4, h = bh & 15;
  const int lane = threadIdx.x & 63, wq = threadIdx.x >> 6;
  const int q32 = lane & 31, hi = lane >> 5;
  const bool lo_half = (hi == 0);
  const int qbase = qb * 128 + wq * 32;
  const int qrow = qbase + q32;

  const ushort* Qb = Q + (size_t)bh * S_LEN * HDIM;
  const ushort* Kb = K + (size_t)bh * S_LEN * HDIM;
  const ushort* Vb = Vt + (size_t)bh * HDIM * S_LEN;

  // Q^T B-frags: lane holds Q[qrow][s*16 + hi*8 .. +7]
  bf16x8 qf[4];
#pragma unroll
  for (int s = 0; s < 4; ++s)
    qf[s] = *(const bf16x8*)&Qb[(size_t)qrow * HDIM + s * 16 + hi * 8];

  f32x16 oacc[2] = {};   // ctx^T tiles: hd 0..31 / 32..63 (cols = q)
  float mraw = -1e30f, lsum = 0.f;
  const float C = 0.125f * 1.44269504f;  // scale * log2(e)

  const int nstep = ((qbase + 31) >> 6) + 1;
  for (int step = 0; step < nstep; ++step) {
    const int kv0 = step * 64;

    // ---- QK^T: S^T[k][q], 2 tiles of 32 k ----
    f32x16 sa[2] = {};
    __builtin_amdgcn_s_setprio(1);
#pragma unroll
    for (int t = 0; t < 2; ++t) {
      const ushort* krow = &Kb[(size_t)(kv0 + t * 32 + q32) * HDIM + hi * 8];
#pragma unroll
      for (int s = 0; s < 4; ++s) {
        bf16x8 kf = *(const bf16x8*)&krow[s * 16];
        sa[t] = __builtin_amdgcn_mfma_f32_32x32x16_bf16(kf, qf[s], sa[t], 0, 0, 0);
      }
    }
    __builtin_amdgcn_s_setprio(0);

    // ---- V^T A-frags (independent; overlap softmax) ----
    bf16x8 vf[2][4];
#pragma unroll
    for (int t2 = 0; t2 < 2; ++t2)
#pragma unroll
      for (int s = 0; s < 4; ++s)
        vf[t2][s] = *(const bf16x8*)&Vb[(size_t)(t2 * 32 + q32) * S_LEN +
                                        kv0 + s * 16 + hi * 8];

    // ---- causal mask (final step only; wave-uniform branch) ----
    if (kv0 + 63 > qbase) {
      const int khi = kv0 + 4 * hi;
#pragma unroll
      for (int t = 0; t < 2; ++t)
#pragma unroll
        for (int r = 0; r < 16; ++r) {
          int kg = khi + t * 32 + (r & 3) + 8 * (r >> 2);
          if (kg > qrow) sa[t][r] = -1e30f;
        }
    }

    // ---- online softmax (raw-score domain; lane-local rows) ----
    float tm = sa[0][0];
#pragma unroll
    for (int r = 1; r < 16; ++r) tm = fmaxf(tm, sa[0][r]);
#pragma unroll
    for (int r = 0; r < 16; ++r) tm = fmaxf(tm, sa[1][r]);
    tm = fmaxf(tm, __shfl_xor(tm, 32, 64));  // combine lane^32 (same q col)

    if (!__all(tm <= mraw + 64.f)) {  // T13 defer-max (64 raw = 8 scaled)
      float mnew = fmaxf(mraw, tm);
      float alpha = __builtin_exp2f((mraw - mnew) * C);
      lsum *= alpha;
#pragma unroll
      for (int r = 0; r < 16; ++r) { oacc[0][r] *= alpha; oacc[1][r] *= alpha; }
      mraw = mnew;
    }
    const float mC = mraw * C;
    float psum = 0.f;
#pragma unroll
    for (int t = 0; t < 2; ++t)
#pragma unroll
      for (int r = 0; r < 16; ++r) {
        float p = __builtin_exp2f(__builtin_fmaf(sa[t][r], C, -mC));
        sa[t][r] = p;
        psum += p;
      }
    lsum += psum + __shfl_xor(psum, 32, 64);

    // ---- P^T -> bf16 B-frags + PV: ctx^T += V^T . P^T ----
    // B-frag word w, lane l: k = (l>>5)*8 + 2w + {0,1}. All shfl_xor are
    // UNCONDITIONAL (convergent, full exec mask); selects are register
    // cndmasks. (Round-4 bug: shfl inside divergent ternary arm -> half-wave
    // exec -> undefined pulls.)
    __builtin_amdgcn_s_setprio(1);
#pragma unroll
    for (int t = 0; t < 2; ++t) {
#pragma unroll
      for (int half = 0; half < 2; ++half) {  // half 0: k 0..15, 1: k 16..31
        const int rb = half * 8;
        unsigned a0 = pack2bf(sa[t][rb + 0], sa[t][rb + 1]);  // k (0,1)|(4,5)
        unsigned a1 = pack2bf(sa[t][rb + 2], sa[t][rb + 3]);  // k (2,3)|(6,7)
        unsigned b0 = pack2bf(sa[t][rb + 4], sa[t][rb + 5]);  // k (8,9)|(12,13)
        unsigned b1 = pack2bf(sa[t][rb + 6], sa[t][rb + 7]);  // k(10,11)|(14,15)
        unsigned xa0 = __shfl_xor(a0, 32, 64);  // partner's a0
        unsigned xa1 = __shfl_xor(a1, 32, 64);
        unsigned xb0 = __shfl_xor(b0, 32, 64);
        unsigned xb1 = __shfl_xor(b1, 32, 64);
        union { unsigned u[4]; bf16x8 v; } pf;
        pf.u[0] = lo_half ? a0 : xb0;   // k0,1 | k8,9
        pf.u[1] = lo_half ? a1 : xb1;   // k2,3 | k10,11
        pf.u[2] = lo_half ? xa0 : b0;   // k4,5 | k12,13
        pf.u[3] = lo_half ? xa1 : b1;   // k6,7 | k14,15
        oacc[0] = __builtin_amdgcn_mfma_f32_32x32x16_bf16(vf[0][t * 2 + half],
                                                          pf.v, oacc[0], 0, 0, 0);
        oacc[1] = __builtin_amdgcn_mfma_f32_32x32x16_bf16(vf[1][t * 2 + half],
                                                          pf.v, oacc[1], 0, 0, 0);
      }
    }
    __builtin_amdgcn_s_setprio(0);
  }

  // ---- epilogue: ctx[b][qrow][h*64+hd] = oacc^T / lsum ----
  const float linv = 1.0f / lsum;
  ushort* crow = &ctx[((size_t)(b * S_LEN) + qrow) * DMODEL + h * HDIM];
#pragma unroll
  for (int t = 0; t < 2; ++t)
#pragma unroll
    for (int g2 = 0; g2 < 4; ++g2) {
      ushort4 o;  // hd = t*32 + g2*8 + hi*4 + r
      o.x = f2bf(oacc[t][g2 * 4 + 0] * linv);
      o.y = f2bf(oacc[t][g2 * 4 + 1] * linv);
      o.z = f2bf(oacc[t][g2 * 4 + 2] * linv);
      o.w = f2bf(oacc[t][g2 * 4 + 3] * linv);
      *(ushort4*)&crow[t * 32 + g2 * 8 + hi * 4] = o;
    }
}

// ---------------- launch ----------------

extern "C" void kernel_launch(void* const* d_in, const int* in_sizes, int n_in,
                              void* d_out, int out_size, void* d_ws,
                              size_t ws_size, hipStream_t stream) {
  const float* x  = (const float*)d_in[0];
  const float* Wq = (const float*)d_in[1];
  const float* bq = (const float*)d_in[2];
  const float* Wk = (const float*)d_in[3];
  const float* bk = (const float*)d_in[4];
  const float* Wv = (const float*)d_in[5];
  const float* bv = (const float*)d_in[6];
  const float* Wo = (const float*)d_in[7];
  const float* bo = (const float*)d_in[8];

  char* ws = (char*)d_ws;
  ushort* Xbf = (ushort*)ws;                               // 8 MB
  ushort* WT  = (ushort*)(ws + (size_t)8 * 1024 * 1024);   // 8 MB
  ushort* QKV = (ushort*)(ws + (size_t)16 * 1024 * 1024);  // 24 MB
  ushort* CTX = (ushort*)(ws + (size_t)40 * 1024 * 1024);  // 8 MB

  const size_t QKV_ELEMS = (size_t)MROWS * DMODEL;
  const size_t W_ELEMS = (size_t)DMODEL * DMODEL;

  cvt_x<<<4096, 256, 0, stream>>>(x, Xbf);
  cvt_wt<<<dim3(32, 32, 4), 256, 0, stream>>>(Wq, Wk, Wv, Wo, WT);
  gemm128<0><<<dim3(32, 8, 3), 256, 0, stream>>>(Xbf, WT, bq, bk, bv, QKV);
  attn2<<<dim3(512), 256, 0, stream>>>(QKV, QKV + QKV_ELEMS,
                                       QKV + 2 * QKV_ELEMS, CTX);
  gemm128<1><<<dim3(32, 8), 256, 0, stream>>>(CTX, WT + 3 * W_ELEMS, bo,
                                              nullptr, nullptr, d_out);
}

// Round 6
// 167.437 us; speedup vs baseline: 1.9629x; 1.2924x over previous
//
#include <hip/hip_runtime.h>

// MHA: B=2, S=2048, D=1024, H=16, HD=64, causal, scale=1/8.
// Round 6: attn3 — causal-balanced paired q-tiles (j & 31-j per block, 33
// steps uniform), K/V staged to LDS via global_load_lds (coalesced, double-
// buffered, 2-phase pipeline), XOR-swizzled (linear dest + inverse-swz global
// source + swz read). 512 blocks x 2 waves. Softmax/PV math = round 5.
//   ws layout (bytes):
//     [0,8M)    Xbf  : x as bf16 [4096,1024]
//     [8M,16M)  WT   : WqT,WkT,WvT,WoT bf16 [1024,1024] each ([N][K])
//     [16M,40M) QKV  : Q [B,H,S,HD], K [B,H,S,HD], Vt [B,H,HD,S] bf16
//     [40M,48M) ctx  : attention output bf16 [B,S,D]

#define S_LEN 2048
#define DMODEL 1024
#define NHEAD 16
#define HDIM 64
#define MROWS 4096  // B*S

typedef __bf16 bf16x8 __attribute__((ext_vector_type(8)));
typedef float f32x4 __attribute__((ext_vector_type(4)));
typedef float f32x16 __attribute__((ext_vector_type(16)));

__device__ __forceinline__ ushort f2bf(float f) {
  union { float f; unsigned u; } v; v.f = f;
  unsigned r = v.u + 0x7fffu + ((v.u >> 16) & 1u);  // RNE
  return (ushort)(r >> 16);
}

__device__ __forceinline__ void gload_lds16(const ushort* g, ushort* l) {
  __builtin_amdgcn_global_load_lds(
      (const __attribute__((address_space(1))) void*)g,
      (__attribute__((address_space(3))) void*)l, 16, 0, 0);
}

// pack two f32 -> one dword of 2 bf16 (compiler emits v_cvt_pk_bf16_f32)
__device__ __forceinline__ unsigned pack2bf(float lo, float hi) {
  union { __bf16 h[2]; unsigned u; } t;
  t.h[0] = (__bf16)lo; t.h[1] = (__bf16)hi;
  return t.u;
}

// ---------------- conversion kernels ----------------

__global__ __launch_bounds__(256) void cvt_x(const float* __restrict__ x,
                                             ushort* __restrict__ xb) {
  int i = (blockIdx.x * 256 + threadIdx.x) * 4;
  float4 v = *(const float4*)&x[i];
  ushort4 o;
  o.x = f2bf(v.x); o.y = f2bf(v.y); o.z = f2bf(v.z); o.w = f2bf(v.w);
  *(ushort4*)&xb[i] = o;
}

// W [K][N] fp32 -> WT [N][K] bf16
__global__ __launch_bounds__(256) void cvt_wt(const float* __restrict__ W0,
                                              const float* __restrict__ W1,
                                              const float* __restrict__ W2,
                                              const float* __restrict__ W3,
                                              ushort* __restrict__ out) {
  const float* W = blockIdx.z == 0 ? W0 : blockIdx.z == 1 ? W1
                   : blockIdx.z == 2 ? W2 : W3;
  ushort* WT = out + (size_t)blockIdx.z * DMODEL * DMODEL;
  __shared__ float tile[32][33];
  int n0 = blockIdx.x * 32, k0 = blockIdx.y * 32;
  int tx = threadIdx.x & 31, ty = threadIdx.x >> 5;  // 32 x 8
#pragma unroll
  for (int i = 0; i < 32; i += 8)
    tile[ty + i][tx] = W[(size_t)(k0 + ty + i) * DMODEL + n0 + tx];
  __syncthreads();
#pragma unroll
  for (int i = 0; i < 32; i += 8)
    WT[(size_t)(n0 + ty + i) * DMODEL + k0 + tx] = f2bf(tile[tx][ty + i]);
}

// ---------------- GEMM (128x128 tile, BK=64, 4 waves) ----------------

template <int MODE>
__global__ __launch_bounds__(256) void gemm128(
    const ushort* __restrict__ A, const ushort* __restrict__ BtB,
    const float* __restrict__ b0, const float* __restrict__ b1,
    const float* __restrict__ b2, void* __restrict__ outB) {
  const int z = (MODE == 0) ? blockIdx.z : 0;
  const ushort* Bt = BtB + (size_t)z * DMODEL * DMODEL;
  const float* bias = (MODE == 0) ? (z == 0 ? b0 : z == 1 ? b1 : b2) : b0;

  __shared__ __align__(16) ushort Alds[128 * 64];
  __shared__ __align__(16) ushort Blds[128 * 64];

  const int tid = threadIdx.x;
  const int lane = tid & 63, w = tid >> 6;
  const int wr = w >> 1, wc = w & 1;
  const int m0 = blockIdx.x * 128, n0 = blockIdx.y * 128;
  const int fr = lane & 15, fk = (lane >> 4) * 8;

  f32x4 acc[4][4] = {};

  for (int kt = 0; kt < DMODEL; kt += 64) {
    __syncthreads();
#pragma unroll
    for (int it = 0; it < 4; ++it) {
      int c = it * 256 + tid;
      int row = c >> 3, col = (c & 7) * 8;
      int ldsbase = (it * 256 + w * 64) * 8;
      gload_lds16(&A[(size_t)(m0 + row) * DMODEL + kt + col], &Alds[ldsbase]);
      gload_lds16(&Bt[(size_t)(n0 + row) * DMODEL + kt + col], &Blds[ldsbase]);
    }
    __syncthreads();
#pragma unroll
    for (int kk = 0; kk < 2; ++kk) {
      bf16x8 af[4], bfr[4];
#pragma unroll
      for (int i = 0; i < 4; ++i)
        af[i] = *(const bf16x8*)&Alds[(wr * 64 + i * 16 + fr) * 64 + kk * 32 + fk];
#pragma unroll
      for (int j = 0; j < 4; ++j)
        bfr[j] = *(const bf16x8*)&Blds[(wc * 64 + j * 16 + fr) * 64 + kk * 32 + fk];
#pragma unroll
      for (int i = 0; i < 4; ++i)
#pragma unroll
        for (int j = 0; j < 4; ++j)
          acc[i][j] = __builtin_amdgcn_mfma_f32_16x16x32_bf16(af[i], bfr[j],
                                                              acc[i][j], 0, 0, 0);
    }
  }

#pragma unroll
  for (int i = 0; i < 4; ++i) {
#pragma unroll
    for (int j = 0; j < 4; ++j) {
      int col = n0 + wc * 64 + j * 16 + fr;
      float bval = bias[col];
#pragma unroll
      for (int r = 0; r < 4; ++r) {
        int row = m0 + wr * 64 + i * 16 + (lane >> 4) * 4 + r;
        float val = acc[i][j][r] + bval;
        if (MODE == 0) {
          int b = row >> 11, s = row & (S_LEN - 1);
          int h = col >> 6, hd = col & (HDIM - 1);
          size_t idx;
          if (z < 2) idx = (((size_t)(b * NHEAD + h)) * S_LEN + s) * HDIM + hd;
          else       idx = (((size_t)(b * NHEAD + h)) * HDIM + hd) * S_LEN + s;
          ((ushort*)outB)[(size_t)z * MROWS * DMODEL + idx] = f2bf(val);
        } else {
          ((float*)outB)[(size_t)row * DMODEL + col] = val;
        }
      }
    }
  }
}

// ---------------- flash attention (causal), LDS-staged, balanced ----------
// 512 blocks x 128 thr (2 waves). Block handles q-tiles j=pair and j=31-pair
// (64 rows each) sequentially -> 33 KV-steps uniform. K/V tiles [64][64]bf16
// staged to LDS (global_load_lds, dbuf); XOR swizzle col16^=(row&7) applied
// on global source + LDS read (linear dest).
__global__ __launch_bounds__(128) void attn3(const ushort* __restrict__ Q,
                                             const ushort* __restrict__ K,
                                             const ushort* __restrict__ Vt,
                                             ushort* __restrict__ ctx) {
  const int n = blockIdx.x;
  const int v = (n & 7) * 64 + (n >> 3);  // bijective XCD-contiguous (512=8*64)
  const int pair = v & 15, bh = v >> 4;
  const int b = bh >> 4, h = bh & 15;
  const int tid = threadIdx.x;
  const int lane = tid & 63, wq = tid >> 6;
  const int q32 = lane & 31, hi = lane >> 5;
  const bool lo_half = (hi == 0);

  const ushort* Qb = Q + (size_t)bh * S_LEN * HDIM;
  const ushort* Kb = K + (size_t)bh * S_LEN * HDIM;
  const ushort* Vb = Vt + (size_t)bh * HDIM * S_LEN;

  __shared__ __align__(16) ushort Kl[2][64 * 64];
  __shared__ __align__(16) ushort Vl[2][64 * 64];

  const float C = 0.125f * 1.44269504f;  // scale * log2(e)

  for (int ph = 0; ph < 2; ++ph) {
    const int j = ph ? 31 - pair : pair;   // 64-row q-tile index, 0..31
    const int qbase = j * 64 + wq * 32;
    const int qrow = qbase + q32;

    bf16x8 qf[4];
#pragma unroll
    for (int s = 0; s < 4; ++s)
      qf[s] = *(const bf16x8*)&Qb[(size_t)qrow * HDIM + s * 16 + hi * 8];

    f32x16 oacc[2] = {};
    float mraw = -1e30f, lsum = 0.f;
    const int nstep = j + 1;

    // prologue: stage step 0 into buf 0 (linear dest, inverse-swz source)
#pragma unroll
    for (int it = 0; it < 4; ++it) {
      int chunk = it * 128 + tid;
      int row = chunk >> 3, sc = ((chunk & 7) ^ (row & 7)) * 8;
      gload_lds16(&Kb[(size_t)row * HDIM + sc], &Kl[0][chunk * 8]);
      gload_lds16(&Vb[(size_t)row * S_LEN + sc], &Vl[0][chunk * 8]);
    }
    __syncthreads();  // drains vmcnt(0)

    for (int step = 0; step < nstep; ++step) {
      const int bi = step & 1;
      const int kv0 = step * 64;
      // issue next-tile stage first (overlaps compute)
      if (step + 1 < nstep) {
        const int kvn = kv0 + 64;
#pragma unroll
        for (int it = 0; it < 4; ++it) {
          int chunk = it * 128 + tid;
          int row = chunk >> 3, sc = ((chunk & 7) ^ (row & 7)) * 8;
          gload_lds16(&Kb[(size_t)(kvn + row) * HDIM + sc],
                      &Kl[bi ^ 1][chunk * 8]);
          gload_lds16(&Vb[(size_t)row * S_LEN + kvn + sc],
                      &Vl[bi ^ 1][chunk * 8]);
        }
      }

      // ---- QK^T: S^T[k][q], 2 tiles of 32 k ----
      f32x16 sa[2] = {};
      __builtin_amdgcn_s_setprio(1);
#pragma unroll
      for (int t = 0; t < 2; ++t) {
        const int row = t * 32 + q32;
        const int rsw = (row & 7);
#pragma unroll
        for (int s = 0; s < 4; ++s) {
          bf16x8 kf = *(const bf16x8*)&Kl[bi][row * 64 + ((s * 2 + hi) ^ rsw) * 8];
          sa[t] = __builtin_amdgcn_mfma_f32_32x32x16_bf16(kf, qf[s], sa[t], 0, 0, 0);
        }
      }
      __builtin_amdgcn_s_setprio(0);

      // ---- V^T A-frags from LDS ----
      bf16x8 vf[2][4];
#pragma unroll
      for (int t2 = 0; t2 < 2; ++t2) {
        const int row = t2 * 32 + q32;
        const int rsw = (row & 7);
#pragma unroll
        for (int s = 0; s < 4; ++s)
          vf[t2][s] = *(const bf16x8*)&Vl[bi][row * 64 + ((s * 2 + hi) ^ rsw) * 8];
      }

      // ---- causal mask (final step only; wave-uniform branch) ----
      if (kv0 + 63 > qbase) {
        const int khi = kv0 + 4 * hi;
#pragma unroll
        for (int t = 0; t < 2; ++t)
#pragma unroll
          for (int r = 0; r < 16; ++r) {
            int kg = khi + t * 32 + (r & 3) + 8 * (r >> 2);
            if (kg > qrow) sa[t][r] = -1e30f;
          }
      }

      // ---- online softmax (raw domain; lane-local rows) ----
      float tm = sa[0][0];
#pragma unroll
      for (int r = 1; r < 16; ++r) tm = fmaxf(tm, sa[0][r]);
#pragma unroll
      for (int r = 0; r < 16; ++r) tm = fmaxf(tm, sa[1][r]);
      tm = fmaxf(tm, __shfl_xor(tm, 32, 64));

      if (!__all(tm <= mraw + 64.f)) {  // T13 defer-max
        float mnew = fmaxf(mraw, tm);
        float alpha = __builtin_exp2f((mraw - mnew) * C);
        lsum *= alpha;
#pragma unroll
        for (int r = 0; r < 16; ++r) { oacc[0][r] *= alpha; oacc[1][r] *= alpha; }
        mraw = mnew;
      }
      const float mC = mraw * C;
      float psum = 0.f;
#pragma unroll
      for (int t = 0; t < 2; ++t)
#pragma unroll
        for (int r = 0; r < 16; ++r) {
          float p = __builtin_exp2f(__builtin_fmaf(sa[t][r], C, -mC));
          sa[t][r] = p;
          psum += p;
        }
      lsum += psum + __shfl_xor(psum, 32, 64);

      // ---- P^T -> bf16 B-frags (unconditional shfl + cndmask) + PV ----
      __builtin_amdgcn_s_setprio(1);
#pragma unroll
      for (int t = 0; t < 2; ++t) {
#pragma unroll
        for (int half = 0; half < 2; ++half) {
          const int rb = half * 8;
          unsigned a0 = pack2bf(sa[t][rb + 0], sa[t][rb + 1]);
          unsigned a1 = pack2bf(sa[t][rb + 2], sa[t][rb + 3]);
          unsigned b0 = pack2bf(sa[t][rb + 4], sa[t][rb + 5]);
          unsigned b1 = pack2bf(sa[t][rb + 6], sa[t][rb + 7]);
          unsigned xa0 = __shfl_xor(a0, 32, 64);
          unsigned xa1 = __shfl_xor(a1, 32, 64);
          unsigned xb0 = __shfl_xor(b0, 32, 64);
          unsigned xb1 = __shfl_xor(b1, 32, 64);
          union { unsigned u[4]; bf16x8 v; } pf;
          pf.u[0] = lo_half ? a0 : xb0;
          pf.u[1] = lo_half ? a1 : xb1;
          pf.u[2] = lo_half ? xa0 : b0;
          pf.u[3] = lo_half ? xa1 : b1;
          oacc[0] = __builtin_amdgcn_mfma_f32_32x32x16_bf16(vf[0][t * 2 + half],
                                                            pf.v, oacc[0], 0, 0, 0);
          oacc[1] = __builtin_amdgcn_mfma_f32_32x32x16_bf16(vf[1][t * 2 + half],
                                                            pf.v, oacc[1], 0, 0, 0);
        }
      }
      __builtin_amdgcn_s_setprio(0);

      __syncthreads();  // stage complete (vmcnt 0) + reads done before overwrite
    }

    // ---- epilogue: ctx[b][qrow][h*64+hd] = oacc^T / lsum ----
    const float linv = 1.0f / lsum;
    ushort* crow = &ctx[((size_t)(b * S_LEN) + qrow) * DMODEL + h * HDIM];
#pragma unroll
    for (int t = 0; t < 2; ++t)
#pragma unroll
      for (int g2 = 0; g2 < 4; ++g2) {
        ushort4 o;  // hd = t*32 + g2*8 + hi*4 + r
        o.x = f2bf(oacc[t][g2 * 4 + 0] * linv);
        o.y = f2bf(oacc[t][g2 * 4 + 1] * linv);
        o.z = f2bf(oacc[t][g2 * 4 + 2] * linv);
        o.w = f2bf(oacc[t][g2 * 4 + 3] * linv);
        *(ushort4*)&crow[t * 32 + g2 * 8 + hi * 4] = o;
      }
  }
}

// ---------------- launch ----------------

extern "C" void kernel_launch(void* const* d_in, const int* in_sizes, int n_in,
                              void* d_out, int out_size, void* d_ws,
                              size_t ws_size, hipStream_t stream) {
  const float* x  = (const float*)d_in[0];
  const float* Wq = (const float*)d_in[1];
  const float* bq = (const float*)d_in[2];
  const float* Wk = (const float*)d_in[3];
  const float* bk = (const float*)d_in[4];
  const float* Wv = (const float*)d_in[5];
  const float* bv = (const float*)d_in[6];
  const float* Wo = (const float*)d_in[7];
  const float* bo = (const float*)d_in[8];

  char* ws = (char*)d_ws;
  ushort* Xbf = (ushort*)ws;                               // 8 MB
  ushort* WT  = (ushort*)(ws + (size_t)8 * 1024 * 1024);   // 8 MB
  ushort* QKV = (ushort*)(ws + (size_t)16 * 1024 * 1024);  // 24 MB
  ushort* CTX = (ushort*)(ws + (size_t)40 * 1024 * 1024);  // 8 MB

  const size_t QKV_ELEMS = (size_t)MROWS * DMODEL;
  const size_t W_ELEMS = (size_t)DMODEL * DMODEL;

  cvt_x<<<4096, 256, 0, stream>>>(x, Xbf);
  cvt_wt<<<dim3(32, 32, 4), 256, 0, stream>>>(Wq, Wk, Wv, Wo, WT);
  gemm128<0><<<dim3(32, 8, 3), 256, 0, stream>>>(Xbf, WT, bq, bk, bv, QKV);
  attn3<<<dim3(512), 128, 0, stream>>>(QKV, QKV + QKV_ELEMS,
                                       QKV + 2 * QKV_ELEMS, CTX);
  gemm128<1><<<dim3(32, 8), 256, 0, stream>>>(CTX, WT + 3 * W_ELEMS, bo,
                                              nullptr, nullptr, d_out);
}

// Round 7
// 145.936 us; speedup vs baseline: 2.2521x; 1.1473x over previous
//
#include <hip/hip_runtime.h>

// MHA: B=2, S=2048, D=1024, H=16, HD=64, causal, scale=1/8.
// Round 7: attn4 — split-KV 4-wave blocks. Waves {0,1} do even KV steps,
// {2,3} odd steps of the same 64-row q-tile (paired j / 31-j, uniform work);
// per-pair double-buffered LDS K/V (64 KB -> 2 blocks/CU -> 8 waves/CU,
// 2x round 6); online-softmax partial merge via LDS at phase end.
// Softmax/PV math identical to round 6. GEMMs unchanged.
//   ws layout (bytes):
//     [0,8M)    Xbf  : x as bf16 [4096,1024]
//     [8M,16M)  WT   : WqT,WkT,WvT,WoT bf16 [1024,1024] each ([N][K])
//     [16M,40M) QKV  : Q [B,H,S,HD], K [B,H,S,HD], Vt [B,H,HD,S] bf16
//     [40M,48M) ctx  : attention output bf16 [B,S,D]

#define S_LEN 2048
#define DMODEL 1024
#define NHEAD 16
#define HDIM 64
#define MROWS 4096  // B*S

typedef __bf16 bf16x8 __attribute__((ext_vector_type(8)));
typedef float f32x4 __attribute__((ext_vector_type(4)));
typedef float f32x16 __attribute__((ext_vector_type(16)));

__device__ __forceinline__ ushort f2bf(float f) {
  union { float f; unsigned u; } v; v.f = f;
  unsigned r = v.u + 0x7fffu + ((v.u >> 16) & 1u);  // RNE
  return (ushort)(r >> 16);
}

__device__ __forceinline__ void gload_lds16(const ushort* g, ushort* l) {
  __builtin_amdgcn_global_load_lds(
      (const __attribute__((address_space(1))) void*)g,
      (__attribute__((address_space(3))) void*)l, 16, 0, 0);
}

// pack two f32 -> one dword of 2 bf16 (compiler emits v_cvt_pk_bf16_f32)
__device__ __forceinline__ unsigned pack2bf(float lo, float hi) {
  union { __bf16 h[2]; unsigned u; } t;
  t.h[0] = (__bf16)lo; t.h[1] = (__bf16)hi;
  return t.u;
}

// ---------------- conversion kernels ----------------

__global__ __launch_bounds__(256) void cvt_x(const float* __restrict__ x,
                                             ushort* __restrict__ xb) {
  int i = (blockIdx.x * 256 + threadIdx.x) * 4;
  float4 v = *(const float4*)&x[i];
  ushort4 o;
  o.x = f2bf(v.x); o.y = f2bf(v.y); o.z = f2bf(v.z); o.w = f2bf(v.w);
  *(ushort4*)&xb[i] = o;
}

// W [K][N] fp32 -> WT [N][K] bf16
__global__ __launch_bounds__(256) void cvt_wt(const float* __restrict__ W0,
                                              const float* __restrict__ W1,
                                              const float* __restrict__ W2,
                                              const float* __restrict__ W3,
                                              ushort* __restrict__ out) {
  const float* W = blockIdx.z == 0 ? W0 : blockIdx.z == 1 ? W1
                   : blockIdx.z == 2 ? W2 : W3;
  ushort* WT = out + (size_t)blockIdx.z * DMODEL * DMODEL;
  __shared__ float tile[32][33];
  int n0 = blockIdx.x * 32, k0 = blockIdx.y * 32;
  int tx = threadIdx.x & 31, ty = threadIdx.x >> 5;  // 32 x 8
#pragma unroll
  for (int i = 0; i < 32; i += 8)
    tile[ty + i][tx] = W[(size_t)(k0 + ty + i) * DMODEL + n0 + tx];
  __syncthreads();
#pragma unroll
  for (int i = 0; i < 32; i += 8)
    WT[(size_t)(n0 + ty + i) * DMODEL + k0 + tx] = f2bf(tile[tx][ty + i]);
}

// ---------------- GEMM (128x128 tile, BK=64, 4 waves) ----------------

template <int MODE>
__global__ __launch_bounds__(256) void gemm128(
    const ushort* __restrict__ A, const ushort* __restrict__ BtB,
    const float* __restrict__ b0, const float* __restrict__ b1,
    const float* __restrict__ b2, void* __restrict__ outB) {
  const int z = (MODE == 0) ? blockIdx.z : 0;
  const ushort* Bt = BtB + (size_t)z * DMODEL * DMODEL;
  const float* bias = (MODE == 0) ? (z == 0 ? b0 : z == 1 ? b1 : b2) : b0;

  __shared__ __align__(16) ushort Alds[128 * 64];
  __shared__ __align__(16) ushort Blds[128 * 64];

  const int tid = threadIdx.x;
  const int lane = tid & 63, w = tid >> 6;
  const int wr = w >> 1, wc = w & 1;
  const int m0 = blockIdx.x * 128, n0 = blockIdx.y * 128;
  const int fr = lane & 15, fk = (lane >> 4) * 8;

  f32x4 acc[4][4] = {};

  for (int kt = 0; kt < DMODEL; kt += 64) {
    __syncthreads();
#pragma unroll
    for (int it = 0; it < 4; ++it) {
      int c = it * 256 + tid;
      int row = c >> 3, col = (c & 7) * 8;
      int ldsbase = (it * 256 + w * 64) * 8;
      gload_lds16(&A[(size_t)(m0 + row) * DMODEL + kt + col], &Alds[ldsbase]);
      gload_lds16(&Bt[(size_t)(n0 + row) * DMODEL + kt + col], &Blds[ldsbase]);
    }
    __syncthreads();
#pragma unroll
    for (int kk = 0; kk < 2; ++kk) {
      bf16x8 af[4], bfr[4];
#pragma unroll
      for (int i = 0; i < 4; ++i)
        af[i] = *(const bf16x8*)&Alds[(wr * 64 + i * 16 + fr) * 64 + kk * 32 + fk];
#pragma unroll
      for (int j = 0; j < 4; ++j)
        bfr[j] = *(const bf16x8*)&Blds[(wc * 64 + j * 16 + fr) * 64 + kk * 32 + fk];
#pragma unroll
      for (int i = 0; i < 4; ++i)
#pragma unroll
        for (int j = 0; j < 4; ++j)
          acc[i][j] = __builtin_amdgcn_mfma_f32_16x16x32_bf16(af[i], bfr[j],
                                                              acc[i][j], 0, 0, 0);
    }
  }

#pragma unroll
  for (int i = 0; i < 4; ++i) {
#pragma unroll
    for (int j = 0; j < 4; ++j) {
      int col = n0 + wc * 64 + j * 16 + fr;
      float bval = bias[col];
#pragma unroll
      for (int r = 0; r < 4; ++r) {
        int row = m0 + wr * 64 + i * 16 + (lane >> 4) * 4 + r;
        float val = acc[i][j][r] + bval;
        if (MODE == 0) {
          int b = row >> 11, s = row & (S_LEN - 1);
          int h = col >> 6, hd = col & (HDIM - 1);
          size_t idx;
          if (z < 2) idx = (((size_t)(b * NHEAD + h)) * S_LEN + s) * HDIM + hd;
          else       idx = (((size_t)(b * NHEAD + h)) * HDIM + hd) * S_LEN + s;
          ((ushort*)outB)[(size_t)z * MROWS * DMODEL + idx] = f2bf(val);
        } else {
          ((float*)outB)[(size_t)row * DMODEL + col] = val;
        }
      }
    }
  }
}

// ---------------- flash attention (causal), split-KV 4-wave ----------------
// 512 blocks x 256 thr. Waves {0,1}: even KV steps; {2,3}: odd steps of the
// same 64-row q-tile. Paired q-tiles j / 31-j per block. Per-pair dbuf LDS
// K/V (XOR-swizzled). Phase-end online-softmax merge via LDS scratch.
__global__ __launch_bounds__(256, 2) void attn4(const ushort* __restrict__ Q,
                                                const ushort* __restrict__ K,
                                                const ushort* __restrict__ Vt,
                                                ushort* __restrict__ ctx) {
  const int n = blockIdx.x;
  const int v = (n & 7) * 64 + (n >> 3);  // bijective XCD-contiguous (512=8*64)
  const int ptile = v & 15, bh = v >> 4;
  const int b = bh >> 4, h = bh & 15;
  const int tid = threadIdx.x;
  const int lane = tid & 63, wid = tid >> 6;
  const int p = wid >> 1;        // KV-parity pair: 0 even steps, 1 odd
  const int wq = wid & 1;        // 32-row q-subtile within the 64-row tile
  const int q32 = lane & 31, hi = lane >> 5;
  const bool lo_half = (hi == 0);
  const int tid2 = tid & 127;    // pair-local thread id (2 waves = 128 thr)

  const ushort* Qb = Q + (size_t)bh * S_LEN * HDIM;
  const ushort* Kb = K + (size_t)bh * S_LEN * HDIM;
  const ushort* Vb = Vt + (size_t)bh * HDIM * S_LEN;

  __shared__ __align__(16) ushort Kl[2][2][64 * 64];  // [pair][buf] 32 KB
  __shared__ __align__(16) ushort Vl[2][2][64 * 64];  // 32 KB
  float* scr = (float*)&Kl[0][0][0];  // merge scratch overlay (post-loop only)

  const float C = 0.125f * 1.44269504f;  // scale * log2(e)

  for (int ph = 0; ph < 2; ++ph) {
    const int j = ph ? 31 - ptile : ptile;  // 64-row q-tile index, 0..31
    const int qbase = j * 64 + wq * 32;
    const int qrow = qbase + q32;

    bf16x8 qf[4];
#pragma unroll
    for (int s = 0; s < 4; ++s)
      qf[s] = *(const bf16x8*)&Qb[(size_t)qrow * HDIM + s * 16 + hi * 8];

    f32x16 oacc[2] = {};
    float mraw = -1e30f, lsum = 0.f;
    const int NS = (j >> 1) + 1;  // iterations (pair0 steps; pair1 <= this)

    // prologue: pair p stages its first step (s0 = p) into buf 0
    if (p <= j) {
      const int kv = p * 64;
#pragma unroll
      for (int it = 0; it < 4; ++it) {
        int chunk = it * 128 + tid2;
        int row = chunk >> 3, sc = ((chunk & 7) ^ (row & 7)) * 8;
        gload_lds16(&Kb[(size_t)(kv + row) * HDIM + sc], &Kl[p][0][chunk * 8]);
        gload_lds16(&Vb[(size_t)row * S_LEN + kv + sc], &Vl[p][0][chunk * 8]);
      }
    }
    __syncthreads();

    int buf = 0;
    for (int it = 0; it < NS; ++it) {
      const int s = 2 * it + p;      // my global KV step
      const int kv0 = s * 64;

      // issue my pair's next-tile stage (s+2) first — overlaps compute
      if (s + 2 <= j) {
        const int kvn = kv0 + 128;
#pragma unroll
        for (int st = 0; st < 4; ++st) {
          int chunk = st * 128 + tid2;
          int row = chunk >> 3, sc = ((chunk & 7) ^ (row & 7)) * 8;
          gload_lds16(&Kb[(size_t)(kvn + row) * HDIM + sc],
                      &Kl[p][buf ^ 1][chunk * 8]);
          gload_lds16(&Vb[(size_t)row * S_LEN + kvn + sc],
                      &Vl[p][buf ^ 1][chunk * 8]);
        }
      }

      if (s <= j) {
        // ---- QK^T: S^T[k][q], 2 tiles of 32 k ----
        f32x16 sa[2] = {};
        __builtin_amdgcn_s_setprio(1);
#pragma unroll
        for (int t = 0; t < 2; ++t) {
          const int row = t * 32 + q32;
          const int rsw = (row & 7);
#pragma unroll
          for (int sl = 0; sl < 4; ++sl) {
            bf16x8 kf = *(const bf16x8*)&Kl[p][buf][row * 64 +
                                                    ((sl * 2 + hi) ^ rsw) * 8];
            sa[t] = __builtin_amdgcn_mfma_f32_32x32x16_bf16(kf, qf[sl], sa[t],
                                                            0, 0, 0);
          }
        }
        __builtin_amdgcn_s_setprio(0);

        // ---- V^T A-frags from LDS ----
        bf16x8 vf[2][4];
#pragma unroll
        for (int t2 = 0; t2 < 2; ++t2) {
          const int row = t2 * 32 + q32;
          const int rsw = (row & 7);
#pragma unroll
          for (int sl = 0; sl < 4; ++sl)
            vf[t2][sl] = *(const bf16x8*)&Vl[p][buf][row * 64 +
                                                     ((sl * 2 + hi) ^ rsw) * 8];
        }

        // ---- causal mask (only step s == j masks; wave-uniform) ----
        if (kv0 + 63 > qbase) {
          const int khi = kv0 + 4 * hi;
#pragma unroll
          for (int t = 0; t < 2; ++t)
#pragma unroll
            for (int r = 0; r < 16; ++r) {
              int kg = khi + t * 32 + (r & 3) + 8 * (r >> 2);
              if (kg > qrow) sa[t][r] = -1e30f;
            }
        }

        // ---- online softmax (raw domain; lane-local rows) ----
        float tm = sa[0][0];
#pragma unroll
        for (int r = 1; r < 16; ++r) tm = fmaxf(tm, sa[0][r]);
#pragma unroll
        for (int r = 0; r < 16; ++r) tm = fmaxf(tm, sa[1][r]);
        tm = fmaxf(tm, __shfl_xor(tm, 32, 64));

        if (!__all(tm <= mraw + 64.f)) {  // T13 defer-max
          float mnew = fmaxf(mraw, tm);
          float alpha = __builtin_exp2f((mraw - mnew) * C);
          lsum *= alpha;
#pragma unroll
          for (int r = 0; r < 16; ++r) { oacc[0][r] *= alpha; oacc[1][r] *= alpha; }
          mraw = mnew;
        }
        const float mC = mraw * C;
        float psum = 0.f;
#pragma unroll
        for (int t = 0; t < 2; ++t)
#pragma unroll
          for (int r = 0; r < 16; ++r) {
            float pp = __builtin_exp2f(__builtin_fmaf(sa[t][r], C, -mC));
            sa[t][r] = pp;
            psum += pp;
          }
        lsum += psum + __shfl_xor(psum, 32, 64);

        // ---- P^T -> bf16 B-frags (unconditional shfl + cndmask) + PV ----
        __builtin_amdgcn_s_setprio(1);
#pragma unroll
        for (int t = 0; t < 2; ++t) {
#pragma unroll
          for (int half = 0; half < 2; ++half) {
            const int rb = half * 8;
            unsigned a0 = pack2bf(sa[t][rb + 0], sa[t][rb + 1]);
            unsigned a1 = pack2bf(sa[t][rb + 2], sa[t][rb + 3]);
            unsigned b0 = pack2bf(sa[t][rb + 4], sa[t][rb + 5]);
            unsigned b1 = pack2bf(sa[t][rb + 6], sa[t][rb + 7]);
            unsigned xa0 = __shfl_xor(a0, 32, 64);
            unsigned xa1 = __shfl_xor(a1, 32, 64);
            unsigned xb0 = __shfl_xor(b0, 32, 64);
            unsigned xb1 = __shfl_xor(b1, 32, 64);
            union { unsigned u[4]; bf16x8 v; } pf;
            pf.u[0] = lo_half ? a0 : xb0;
            pf.u[1] = lo_half ? a1 : xb1;
            pf.u[2] = lo_half ? xa0 : b0;
            pf.u[3] = lo_half ? xa1 : b1;
            oacc[0] = __builtin_amdgcn_mfma_f32_32x32x16_bf16(
                vf[0][t * 2 + half], pf.v, oacc[0], 0, 0, 0);
            oacc[1] = __builtin_amdgcn_mfma_f32_32x32x16_bf16(
                vf[1][t * 2 + half], pf.v, oacc[1], 0, 0, 0);
          }
        }
        __builtin_amdgcn_s_setprio(0);
      }

      __syncthreads();  // stage complete + LDS reads done before overwrite
      buf ^= 1;
    }

    // ---- merge pair partials: pair1 publishes, pair0 merges + stores ----
    const int base = (wq * 64 + lane) * 37;  // stride-37: conflict-free
    if (p == 1) {
      scr[base + 0] = mraw;
      scr[base + 1] = lsum;
#pragma unroll
      for (int t = 0; t < 2; ++t)
#pragma unroll
        for (int r = 0; r < 16; ++r) scr[base + 2 + t * 16 + r] = oacc[t][r];
    }
    __syncthreads();
    if (p == 0) {
      const float mB = scr[base + 0], lB = scr[base + 1];
      const float mS = fmaxf(mraw, mB);
      const float aA = __builtin_exp2f((mraw - mS) * C);
      const float aB = __builtin_exp2f((mB - mS) * C);
      const float lT = lsum * aA + lB * aB;
      const float linv = 1.0f / lT;
      ushort* crow = &ctx[((size_t)(b * S_LEN) + qrow) * DMODEL + h * HDIM];
#pragma unroll
      for (int t = 0; t < 2; ++t)
#pragma unroll
        for (int g2 = 0; g2 < 4; ++g2) {
          ushort4 o;  // hd = t*32 + g2*8 + hi*4 + r
          float m0 = oacc[t][g2 * 4 + 0] * aA + scr[base + 2 + t * 16 + g2 * 4 + 0] * aB;
          float m1 = oacc[t][g2 * 4 + 1] * aA + scr[base + 2 + t * 16 + g2 * 4 + 1] * aB;
          float m2 = oacc[t][g2 * 4 + 2] * aA + scr[base + 2 + t * 16 + g2 * 4 + 2] * aB;
          float m3 = oacc[t][g2 * 4 + 3] * aA + scr[base + 2 + t * 16 + g2 * 4 + 3] * aB;
          o.x = f2bf(m0 * linv); o.y = f2bf(m1 * linv);
          o.z = f2bf(m2 * linv); o.w = f2bf(m3 * linv);
          *(ushort4*)&crow[t * 32 + g2 * 8 + hi * 4] = o;
        }
    }
    __syncthreads();  // scratch reads done before next phase restages LDS
  }
}

// ---------------- launch ----------------

extern "C" void kernel_launch(void* const* d_in, const int* in_sizes, int n_in,
                              void* d_out, int out_size, void* d_ws,
                              size_t ws_size, hipStream_t stream) {
  const float* x  = (const float*)d_in[0];
  const float* Wq = (const float*)d_in[1];
  const float* bq = (const float*)d_in[2];
  const float* Wk = (const float*)d_in[3];
  const float* bk = (const float*)d_in[4];
  const float* Wv = (const float*)d_in[5];
  const float* bv = (const float*)d_in[6];
  const float* Wo = (const float*)d_in[7];
  const float* bo = (const float*)d_in[8];

  char* ws = (char*)d_ws;
  ushort* Xbf = (ushort*)ws;                               // 8 MB
  ushort* WT  = (ushort*)(ws + (size_t)8 * 1024 * 1024);   // 8 MB
  ushort* QKV = (ushort*)(ws + (size_t)16 * 1024 * 1024);  // 24 MB
  ushort* CTX = (ushort*)(ws + (size_t)40 * 1024 * 1024);  // 8 MB

  const size_t QKV_ELEMS = (size_t)MROWS * DMODEL;
  const size_t W_ELEMS = (size_t)DMODEL * DMODEL;

  cvt_x<<<4096, 256, 0, stream>>>(x, Xbf);
  cvt_wt<<<dim3(32, 32, 4), 256, 0, stream>>>(Wq, Wk, Wv, Wo, WT);
  gemm128<0><<<dim3(32, 8, 3), 256, 0, stream>>>(Xbf, WT, bq, bk, bv, QKV);
  attn4<<<dim3(512), 256, 0, stream>>>(QKV, QKV + QKV_ELEMS,
                                       QKV + 2 * QKV_ELEMS, CTX);
  gemm128<1><<<dim3(32, 8), 256, 0, stream>>>(CTX, WT + 3 * W_ELEMS, bo,
                                              nullptr, nullptr, d_out);
}

// Round 8
// 142.545 us; speedup vs baseline: 2.3057x; 1.0238x over previous
//
#include <hip/hip_runtime.h>

// MHA: B=2, S=2048, D=1024, H=16, HD=64, causal, scale=1/8.
// Round 8: GEMM restructure — (a) T3-minimum 2-phase overlap: double-buffered
// LDS, STAGE(t+1) issued before COMPUTE(t), one barrier/tile; (b) QKV fused
// into one N=3072 dispatch; (c) bijective XCD block swizzle; (d) both-sides
// XOR LDS swizzle (verified attn3 pattern). attn4 unchanged from round 7.
//   ws layout (bytes):
//     [0,8M)    Xbf  : x as bf16 [4096,1024]
//     [8M,16M)  WT   : WqT,WkT,WvT,WoT bf16 [1024,1024] each ([N][K])
//     [16M,40M) QKV  : Q [B,H,S,HD], K [B,H,S,HD], Vt [B,H,HD,S] bf16
//     [40M,48M) ctx  : attention output bf16 [B,S,D]

#define S_LEN 2048
#define DMODEL 1024
#define NHEAD 16
#define HDIM 64
#define MROWS 4096  // B*S

typedef __bf16 bf16x8 __attribute__((ext_vector_type(8)));
typedef float f32x4 __attribute__((ext_vector_type(4)));
typedef float f32x16 __attribute__((ext_vector_type(16)));

__device__ __forceinline__ ushort f2bf(float f) {
  union { float f; unsigned u; } v; v.f = f;
  unsigned r = v.u + 0x7fffu + ((v.u >> 16) & 1u);  // RNE
  return (ushort)(r >> 16);
}

__device__ __forceinline__ void gload_lds16(const ushort* g, ushort* l) {
  __builtin_amdgcn_global_load_lds(
      (const __attribute__((address_space(1))) void*)g,
      (__attribute__((address_space(3))) void*)l, 16, 0, 0);
}

// pack two f32 -> one dword of 2 bf16 (compiler emits v_cvt_pk_bf16_f32)
__device__ __forceinline__ unsigned pack2bf(float lo, float hi) {
  union { __bf16 h[2]; unsigned u; } t;
  t.h[0] = (__bf16)lo; t.h[1] = (__bf16)hi;
  return t.u;
}

// ---------------- conversion kernels ----------------

__global__ __launch_bounds__(256) void cvt_x(const float* __restrict__ x,
                                             ushort* __restrict__ xb) {
  int i = (blockIdx.x * 256 + threadIdx.x) * 4;
  float4 v = *(const float4*)&x[i];
  ushort4 o;
  o.x = f2bf(v.x); o.y = f2bf(v.y); o.z = f2bf(v.z); o.w = f2bf(v.w);
  *(ushort4*)&xb[i] = o;
}

// W [K][N] fp32 -> WT [N][K] bf16
__global__ __launch_bounds__(256) void cvt_wt(const float* __restrict__ W0,
                                              const float* __restrict__ W1,
                                              const float* __restrict__ W2,
                                              const float* __restrict__ W3,
                                              ushort* __restrict__ out) {
  const float* W = blockIdx.z == 0 ? W0 : blockIdx.z == 1 ? W1
                   : blockIdx.z == 2 ? W2 : W3;
  ushort* WT = out + (size_t)blockIdx.z * DMODEL * DMODEL;
  __shared__ float tile[32][33];
  int n0 = blockIdx.x * 32, k0 = blockIdx.y * 32;
  int tx = threadIdx.x & 31, ty = threadIdx.x >> 5;  // 32 x 8
#pragma unroll
  for (int i = 0; i < 32; i += 8)
    tile[ty + i][tx] = W[(size_t)(k0 + ty + i) * DMODEL + n0 + tx];
  __syncthreads();
#pragma unroll
  for (int i = 0; i < 32; i += 8)
    WT[(size_t)(n0 + ty + i) * DMODEL + k0 + tx] = f2bf(tile[tx][ty + i]);
}

// ---------------- GEMM (128x128 tile, BK=64, 4 waves, 2-phase dbuf) -------
// A [M,1024] bf16; Bt [N,1024] bf16 ([N][K]).  MODE 0: N=3072 fused QKV
// (z = col>>10 selects Q/K/Vt layout + bias; bf16 out at z-offset).
// MODE 1: N=1024, fp32 plain [M,N] out (+bias b0).
// LDS both-sides XOR swizzle: linear dest chunks; source col-chunk ^= row&7;
// read chunk ^= row&7.

template <int MODE>
__global__ __launch_bounds__(256) void gemm128(
    const ushort* __restrict__ A, const ushort* __restrict__ Bt,
    const float* __restrict__ b0, const float* __restrict__ b1,
    const float* __restrict__ b2, void* __restrict__ outB) {
  const int NT = (MODE == 0) ? 768 : 256;  // total blocks (32 x 24|8)
  const int flat = blockIdx.y * 32 + blockIdx.x;
  const int swz = (flat & 7) * (NT >> 3) + (flat >> 3);  // bijective (NT%8==0)
  const int bx = swz & 31, by = swz >> 5;
  const int m0 = bx * 128, n0 = by * 128;

  __shared__ __align__(16) ushort Alds[2][128 * 64];
  __shared__ __align__(16) ushort Blds[2][128 * 64];

  const int tid = threadIdx.x;
  const int lane = tid & 63, w = tid >> 6;
  const int wr = w >> 1, wc = w & 1;
  const int fr = lane & 15, hi16 = lane >> 4;
  const int fk = hi16 * 8;

  f32x4 acc[4][4] = {};

  auto STAGE = [&](int kt, int bi) {
#pragma unroll
    for (int it = 0; it < 4; ++it) {
      int c = it * 256 + tid;                    // 16B chunk index 0..1023
      int row = c >> 3;
      int sc = ((c & 7) ^ (row & 7)) * 8;        // inverse-swizzled source col
      int ldsbase = (it * 256 + w * 64) * 8;     // linear wave-uniform dest
      gload_lds16(&A[(size_t)(m0 + row) * DMODEL + kt + sc],
                  &Alds[bi][ldsbase]);
      gload_lds16(&Bt[(size_t)(n0 + row) * DMODEL + kt + sc],
                  &Blds[bi][ldsbase]);
    }
  };

  auto COMPUTE = [&](int bi) {
#pragma unroll
    for (int kk = 0; kk < 2; ++kk) {
      bf16x8 af[4], bfr[4];
#pragma unroll
      for (int i = 0; i < 4; ++i) {
        int row = wr * 64 + i * 16 + fr;
        af[i] = *(const bf16x8*)&Alds[bi][row * 64 +
                                          ((kk * 4 + hi16) ^ (row & 7)) * 8];
      }
#pragma unroll
      for (int j = 0; j < 4; ++j) {
        int row = wc * 64 + j * 16 + fr;
        bfr[j] = *(const bf16x8*)&Blds[bi][row * 64 +
                                           ((kk * 4 + hi16) ^ (row & 7)) * 8];
      }
#pragma unroll
      for (int i = 0; i < 4; ++i)
#pragma unroll
        for (int j = 0; j < 4; ++j)
          acc[i][j] = __builtin_amdgcn_mfma_f32_16x16x32_bf16(af[i], bfr[j],
                                                              acc[i][j], 0, 0, 0);
    }
  };

  STAGE(0, 0);
  __syncthreads();  // vmcnt(0) drained: buf0 ready
  int buf = 0;
  for (int kt = 64; kt < DMODEL; kt += 64) {
    STAGE(kt, buf ^ 1);   // issue next tile first — hides under compute
    COMPUTE(buf);
    __syncthreads();      // stage complete + reads done before overwrite
    buf ^= 1;
  }
  COMPUTE(buf);

  // ---- epilogue ----
#pragma unroll
  for (int i = 0; i < 4; ++i) {
#pragma unroll
    for (int j = 0; j < 4; ++j) {
      int col = n0 + wc * 64 + j * 16 + fr;   // 0..3071 (MODE0) / 0..1023
      int z = col >> 10, cw = col & 1023;
      float bval = (MODE == 0)
                       ? (z == 0 ? b0[cw] : z == 1 ? b1[cw] : b2[cw])
                       : b0[col];
#pragma unroll
      for (int r = 0; r < 4; ++r) {
        int row = m0 + wr * 64 + i * 16 + hi16 * 4 + r;
        float val = acc[i][j][r] + bval;
        if (MODE == 0) {
          int b = row >> 11, s = row & (S_LEN - 1);
          int h = cw >> 6, hd = cw & (HDIM - 1);
          size_t idx;
          if (z < 2) idx = (((size_t)(b * NHEAD + h)) * S_LEN + s) * HDIM + hd;
          else       idx = (((size_t)(b * NHEAD + h)) * HDIM + hd) * S_LEN + s;
          ((ushort*)outB)[(size_t)z * MROWS * DMODEL + idx] = f2bf(val);
        } else {
          ((float*)outB)[(size_t)row * DMODEL + col] = val;
        }
      }
    }
  }
}

// ---------------- flash attention (causal), split-KV 4-wave ----------------
// 512 blocks x 256 thr. Waves {0,1}: even KV steps; {2,3}: odd steps of the
// same 64-row q-tile. Paired q-tiles j / 31-j per block. Per-pair dbuf LDS
// K/V (XOR-swizzled). Phase-end online-softmax merge via LDS scratch.
__global__ __launch_bounds__(256, 2) void attn4(const ushort* __restrict__ Q,
                                                const ushort* __restrict__ K,
                                                const ushort* __restrict__ Vt,
                                                ushort* __restrict__ ctx) {
  const int n = blockIdx.x;
  const int v = (n & 7) * 64 + (n >> 3);  // bijective XCD-contiguous (512=8*64)
  const int ptile = v & 15, bh = v >> 4;
  const int b = bh >> 4, h = bh & 15;
  const int tid = threadIdx.x;
  const int lane = tid & 63, wid = tid >> 6;
  const int p = wid >> 1;        // KV-parity pair: 0 even steps, 1 odd
  const int wq = wid & 1;        // 32-row q-subtile within the 64-row tile
  const int q32 = lane & 31, hi = lane >> 5;
  const bool lo_half = (hi == 0);
  const int tid2 = tid & 127;    // pair-local thread id (2 waves = 128 thr)

  const ushort* Qb = Q + (size_t)bh * S_LEN * HDIM;
  const ushort* Kb = K + (size_t)bh * S_LEN * HDIM;
  const ushort* Vb = Vt + (size_t)bh * HDIM * S_LEN;

  __shared__ __align__(16) ushort Kl[2][2][64 * 64];  // [pair][buf] 32 KB
  __shared__ __align__(16) ushort Vl[2][2][64 * 64];  // 32 KB
  float* scr = (float*)&Kl[0][0][0];  // merge scratch overlay (post-loop only)

  const float C = 0.125f * 1.44269504f;  // scale * log2(e)

  for (int ph = 0; ph < 2; ++ph) {
    const int j = ph ? 31 - ptile : ptile;  // 64-row q-tile index, 0..31
    const int qbase = j * 64 + wq * 32;
    const int qrow = qbase + q32;

    bf16x8 qf[4];
#pragma unroll
    for (int s = 0; s < 4; ++s)
      qf[s] = *(const bf16x8*)&Qb[(size_t)qrow * HDIM + s * 16 + hi * 8];

    f32x16 oacc[2] = {};
    float mraw = -1e30f, lsum = 0.f;
    const int NS = (j >> 1) + 1;  // iterations (pair0 steps; pair1 <= this)

    // prologue: pair p stages its first step (s0 = p) into buf 0
    if (p <= j) {
      const int kv = p * 64;
#pragma unroll
      for (int it = 0; it < 4; ++it) {
        int chunk = it * 128 + tid2;
        int row = chunk >> 3, sc = ((chunk & 7) ^ (row & 7)) * 8;
        gload_lds16(&Kb[(size_t)(kv + row) * HDIM + sc], &Kl[p][0][chunk * 8]);
        gload_lds16(&Vb[(size_t)row * S_LEN + kv + sc], &Vl[p][0][chunk * 8]);
      }
    }
    __syncthreads();

    int buf = 0;
    for (int it = 0; it < NS; ++it) {
      const int s = 2 * it + p;      // my global KV step
      const int kv0 = s * 64;

      // issue my pair's next-tile stage (s+2) first — overlaps compute
      if (s + 2 <= j) {
        const int kvn = kv0 + 128;
#pragma unroll
        for (int st = 0; st < 4; ++st) {
          int chunk = st * 128 + tid2;
          int row = chunk >> 3, sc = ((chunk & 7) ^ (row & 7)) * 8;
          gload_lds16(&Kb[(size_t)(kvn + row) * HDIM + sc],
                      &Kl[p][buf ^ 1][chunk * 8]);
          gload_lds16(&Vb[(size_t)row * S_LEN + kvn + sc],
                      &Vl[p][buf ^ 1][chunk * 8]);
        }
      }

      if (s <= j) {
        // ---- QK^T: S^T[k][q], 2 tiles of 32 k ----
        f32x16 sa[2] = {};
        __builtin_amdgcn_s_setprio(1);
#pragma unroll
        for (int t = 0; t < 2; ++t) {
          const int row = t * 32 + q32;
          const int rsw = (row & 7);
#pragma unroll
          for (int sl = 0; sl < 4; ++sl) {
            bf16x8 kf = *(const bf16x8*)&Kl[p][buf][row * 64 +
                                                    ((sl * 2 + hi) ^ rsw) * 8];
            sa[t] = __builtin_amdgcn_mfma_f32_32x32x16_bf16(kf, qf[sl], sa[t],
                                                            0, 0, 0);
          }
        }
        __builtin_amdgcn_s_setprio(0);

        // ---- V^T A-frags from LDS ----
        bf16x8 vf[2][4];
#pragma unroll
        for (int t2 = 0; t2 < 2; ++t2) {
          const int row = t2 * 32 + q32;
          const int rsw = (row & 7);
#pragma unroll
          for (int sl = 0; sl < 4; ++sl)
            vf[t2][sl] = *(const bf16x8*)&Vl[p][buf][row * 64 +
                                                     ((sl * 2 + hi) ^ rsw) * 8];
        }

        // ---- causal mask (only step s == j masks; wave-uniform) ----
        if (kv0 + 63 > qbase) {
          const int khi = kv0 + 4 * hi;
#pragma unroll
          for (int t = 0; t < 2; ++t)
#pragma unroll
            for (int r = 0; r < 16; ++r) {
              int kg = khi + t * 32 + (r & 3) + 8 * (r >> 2);
              if (kg > qrow) sa[t][r] = -1e30f;
            }
        }

        // ---- online softmax (raw domain; lane-local rows) ----
        float tm = sa[0][0];
#pragma unroll
        for (int r = 1; r < 16; ++r) tm = fmaxf(tm, sa[0][r]);
#pragma unroll
        for (int r = 0; r < 16; ++r) tm = fmaxf(tm, sa[1][r]);
        tm = fmaxf(tm, __shfl_xor(tm, 32, 64));

        if (!__all(tm <= mraw + 64.f)) {  // T13 defer-max
          float mnew = fmaxf(mraw, tm);
          float alpha = __builtin_exp2f((mraw - mnew) * C);
          lsum *= alpha;
#pragma unroll
          for (int r = 0; r < 16; ++r) { oacc[0][r] *= alpha; oacc[1][r] *= alpha; }
          mraw = mnew;
        }
        const float mC = mraw * C;
        float psum = 0.f;
#pragma unroll
        for (int t = 0; t < 2; ++t)
#pragma unroll
          for (int r = 0; r < 16; ++r) {
            float pp = __builtin_exp2f(__builtin_fmaf(sa[t][r], C, -mC));
            sa[t][r] = pp;
            psum += pp;
          }
        lsum += psum + __shfl_xor(psum, 32, 64);

        // ---- P^T -> bf16 B-frags (unconditional shfl + cndmask) + PV ----
        __builtin_amdgcn_s_setprio(1);
#pragma unroll
        for (int t = 0; t < 2; ++t) {
#pragma unroll
          for (int half = 0; half < 2; ++half) {
            const int rb = half * 8;
            unsigned a0 = pack2bf(sa[t][rb + 0], sa[t][rb + 1]);
            unsigned a1 = pack2bf(sa[t][rb + 2], sa[t][rb + 3]);
            unsigned b0w = pack2bf(sa[t][rb + 4], sa[t][rb + 5]);
            unsigned b1w = pack2bf(sa[t][rb + 6], sa[t][rb + 7]);
            unsigned xa0 = __shfl_xor(a0, 32, 64);
            unsigned xa1 = __shfl_xor(a1, 32, 64);
            unsigned xb0 = __shfl_xor(b0w, 32, 64);
            unsigned xb1 = __shfl_xor(b1w, 32, 64);
            union { unsigned u[4]; bf16x8 v; } pf;
            pf.u[0] = lo_half ? a0 : xb0;
            pf.u[1] = lo_half ? a1 : xb1;
            pf.u[2] = lo_half ? xa0 : b0w;
            pf.u[3] = lo_half ? xa1 : b1w;
            oacc[0] = __builtin_amdgcn_mfma_f32_32x32x16_bf16(
                vf[0][t * 2 + half], pf.v, oacc[0], 0, 0, 0);
            oacc[1] = __builtin_amdgcn_mfma_f32_32x32x16_bf16(
                vf[1][t * 2 + half], pf.v, oacc[1], 0, 0, 0);
          }
        }
        __builtin_amdgcn_s_setprio(0);
      }

      __syncthreads();  // stage complete + LDS reads done before overwrite
      buf ^= 1;
    }

    // ---- merge pair partials: pair1 publishes, pair0 merges + stores ----
    const int base = (wq * 64 + lane) * 37;  // stride-37: conflict-free
    if (p == 1) {
      scr[base + 0] = mraw;
      scr[base + 1] = lsum;
#pragma unroll
      for (int t = 0; t < 2; ++t)
#pragma unroll
        for (int r = 0; r < 16; ++r) scr[base + 2 + t * 16 + r] = oacc[t][r];
    }
    __syncthreads();
    if (p == 0) {
      const float mB = scr[base + 0], lB = scr[base + 1];
      const float mS = fmaxf(mraw, mB);
      const float aA = __builtin_exp2f((mraw - mS) * C);
      const float aB = __builtin_exp2f((mB - mS) * C);
      const float lT = lsum * aA + lB * aB;
      const float linv = 1.0f / lT;
      ushort* crow = &ctx[((size_t)(b * S_LEN) + qrow) * DMODEL + h * HDIM];
#pragma unroll
      for (int t = 0; t < 2; ++t)
#pragma unroll
        for (int g2 = 0; g2 < 4; ++g2) {
          ushort4 o;  // hd = t*32 + g2*8 + hi*4 + r
          float m0 = oacc[t][g2 * 4 + 0] * aA + scr[base + 2 + t * 16 + g2 * 4 + 0] * aB;
          float m1 = oacc[t][g2 * 4 + 1] * aA + scr[base + 2 + t * 16 + g2 * 4 + 1] * aB;
          float m2 = oacc[t][g2 * 4 + 2] * aA + scr[base + 2 + t * 16 + g2 * 4 + 2] * aB;
          float m3 = oacc[t][g2 * 4 + 3] * aA + scr[base + 2 + t * 16 + g2 * 4 + 3] * aB;
          o.x = f2bf(m0 * linv); o.y = f2bf(m1 * linv);
          o.z = f2bf(m2 * linv); o.w = f2bf(m3 * linv);
          *(ushort4*)&crow[t * 32 + g2 * 8 + hi * 4] = o;
        }
    }
    __syncthreads();  // scratch reads done before next phase restages LDS
  }
}

// ---------------- launch ----------------

extern "C" void kernel_launch(void* const* d_in, const int* in_sizes, int n_in,
                              void* d_out, int out_size, void* d_ws,
                              size_t ws_size, hipStream_t stream) {
  const float* x  = (const float*)d_in[0];
  const float* Wq = (const float*)d_in[1];
  const float* bq = (const float*)d_in[2];
  const float* Wk = (const float*)d_in[3];
  const float* bk = (const float*)d_in[4];
  const float* Wv = (const float*)d_in[5];
  const float* bv = (const float*)d_in[6];
  const float* Wo = (const float*)d_in[7];
  const float* bo = (const float*)d_in[8];

  char* ws = (char*)d_ws;
  ushort* Xbf = (ushort*)ws;                               // 8 MB
  ushort* WT  = (ushort*)(ws + (size_t)8 * 1024 * 1024);   // 8 MB
  ushort* QKV = (ushort*)(ws + (size_t)16 * 1024 * 1024);  // 24 MB
  ushort* CTX = (ushort*)(ws + (size_t)40 * 1024 * 1024);  // 8 MB

  const size_t QKV_ELEMS = (size_t)MROWS * DMODEL;
  const size_t W_ELEMS = (size_t)DMODEL * DMODEL;

  cvt_x<<<4096, 256, 0, stream>>>(x, Xbf);
  cvt_wt<<<dim3(32, 32, 4), 256, 0, stream>>>(Wq, Wk, Wv, Wo, WT);
  gemm128<0><<<dim3(32, 24), 256, 0, stream>>>(Xbf, WT, bq, bk, bv, QKV);
  attn4<<<dim3(512), 256, 0, stream>>>(QKV, QKV + QKV_ELEMS,
                                       QKV + 2 * QKV_ELEMS, CTX);
  gemm128<1><<<dim3(32, 8), 256, 0, stream>>>(CTX, WT + 3 * W_ELEMS, bo,
                                              nullptr, nullptr, d_out);
}